// Round 2
// baseline (6160.058 us; speedup 1.0000x reference)
//
#include <hip/hip_runtime.h>
#include <hip/hip_bf16.h>
#include <math.h>

#define LEN 65536
#define LOUT 64536
typedef __hip_bfloat16 bf16;

__device__ inline float b2f(bf16 h) { return __bfloat162float(h); }
__device__ inline bf16 f2b(float f) { return __float2bfloat16(f); }

// ============ Kernel 1: motif conv (4->40, K=51, pad25) + softplus + reduce(40->4) ============
// grid (128, nb), block 256; each thread computes 2 strided l positions (tile 512)
__global__ __launch_bounds__(256) void k_motif(const float* __restrict__ x,
        const float* __restrict__ w_motif, const float* __restrict__ b_motif,
        const float* __restrict__ w_reduce, const float* __restrict__ b_reduce,
        bf16* __restrict__ y, float* __restrict__ s1, int b0) {
    __shared__ float xs[4][564];                 // tile 512 + halo 52
    __shared__ __align__(16) float wsm[40 * 4 * 52]; // k padded 51->52 (pad=0)
    __shared__ float wred[160];
    const int tid = threadIdx.x;
    const int t = blockIdx.x, bl = blockIdx.y;   // bl: local (ws) batch
    const int bg = b0 + bl;                      // bg: global batch
    const int l0 = t * 512;

    for (int i = tid; i < 40 * 4 * 52; i += 256) {
        int k = i % 52, oc = i / 52;
        wsm[i] = (k < 51) ? w_motif[oc * 51 + k] : 0.f;
    }
    for (int i = tid; i < 160; i += 256) wred[i] = w_reduce[i];
    for (int p = tid; p < 564; p += 256) {
        int g = l0 - 25 + p;
        bool ok = (g >= 0 && g < LEN);
        #pragma unroll
        for (int c = 0; c < 4; ++c)
            xs[c][p] = ok ? x[((size_t)bg * 4 + c) * LEN + g] : 0.f;
    }
    __syncthreads();

    float acc[40][2];
    #pragma unroll
    for (int o = 0; o < 40; ++o) { acc[o][0] = 0.f; acc[o][1] = 0.f; }

    for (int c = 0; c < 4; ++c) {
        for (int k0 = 0; k0 < 52; k0 += 4) {
            float xv[2][4];
            #pragma unroll
            for (int j = 0; j < 2; ++j)
                #pragma unroll
                for (int dk = 0; dk < 4; ++dk)
                    xv[j][dk] = xs[c][tid + j * 256 + k0 + dk];
            #pragma unroll
            for (int o = 0; o < 40; ++o) {
                const float4 wv = *(const float4*)&wsm[(o * 4 + c) * 52 + k0];
                #pragma unroll
                for (int j = 0; j < 2; ++j)
                    acc[o][j] += wv.x * xv[j][0] + wv.y * xv[j][1]
                               + wv.z * xv[j][2] + wv.w * xv[j][3];
            }
        }
    }

    #pragma unroll
    for (int j = 0; j < 2; ++j) {
        const int l = l0 + tid + j * 256;
        float s[4] = {0.f, 0.f, 0.f, 0.f};
        #pragma unroll
        for (int o = 0; o < 40; ++o) {
            float v = acc[o][j] + b_motif[o];
            float yv = (v > 20.f) ? v : log1pf(__expf(v));   // softplus
            y[((size_t)bl * 40 + o) * LEN + l] = f2b(yv);
            #pragma unroll
            for (int c = 0; c < 4; ++c) s[c] += wred[c * 40 + o] * yv;
        }
        #pragma unroll
        for (int c = 0; c < 4; ++c)
            s1[((size_t)bl * 4 + c) * LEN + l] = s[c] + b_reduce[c];
    }
}

// ============ Kernel 2: fft conv (4->4, K=401, pad 200) ============
// grid (64, nb), block 256; each thread 4 strided positions (tile 1024)
__global__ __launch_bounds__(256) void k_fft(const float* __restrict__ s1,
        const float* __restrict__ w_fft, const float* __restrict__ b_fft,
        float* __restrict__ s2) {
    __shared__ float xs[4][1428];                  // 1024 + 404
    __shared__ __align__(16) float wsf[4 * 4 * 404]; // k padded 401->404
    const int tid = threadIdx.x;
    const int t = blockIdx.x, bl = blockIdx.y;
    const int l0 = t * 1024;

    for (int i = tid; i < 4 * 4 * 404; i += 256) {
        int k = i % 404, oc = i / 404;
        wsf[i] = (k < 401) ? w_fft[oc * 401 + k] : 0.f;
    }
    for (int p = tid; p < 1428; p += 256) {
        int g = l0 - 200 + p;
        bool ok = (g >= 0 && g < LEN);
        #pragma unroll
        for (int c = 0; c < 4; ++c)
            xs[c][p] = ok ? s1[((size_t)bl * 4 + c) * LEN + g] : 0.f;
    }
    __syncthreads();

    float acc[4][4]; // [o][j]
    #pragma unroll
    for (int o = 0; o < 4; ++o)
        #pragma unroll
        for (int j = 0; j < 4; ++j) acc[o][j] = 0.f;

    for (int c = 0; c < 4; ++c) {
        for (int k0 = 0; k0 < 404; k0 += 4) {
            float xv[4][4]; // [j][dk]
            #pragma unroll
            for (int j = 0; j < 4; ++j)
                #pragma unroll
                for (int dk = 0; dk < 4; ++dk)
                    xv[j][dk] = xs[c][tid + j * 256 + k0 + dk];
            #pragma unroll
            for (int o = 0; o < 4; ++o) {
                const float4 wv = *(const float4*)&wsf[(o * 4 + c) * 404 + k0];
                #pragma unroll
                for (int j = 0; j < 4; ++j)
                    acc[o][j] += wv.x * xv[j][0] + wv.y * xv[j][1]
                               + wv.z * xv[j][2] + wv.w * xv[j][3];
            }
        }
    }

    #pragma unroll
    for (int o = 0; o < 4; ++o) {
        float bb = b_fft[o];
        #pragma unroll
        for (int j = 0; j < 4; ++j)
            s2[((size_t)bl * 4 + o) * LEN + l0 + tid + j * 256] = acc[o][j] + bb;
    }
}

// ============ Kernel 3: expand (4->40, 1x1) + sigmoid gate, in-place motifact over y ============
// grid (64, nb), block 256, 4 consecutive positions per thread
__global__ __launch_bounds__(256) void k_gate(const float* __restrict__ s2,
        const float* __restrict__ w_expand, const float* __restrict__ b_expand,
        bf16* __restrict__ y) {
    const int tid = threadIdx.x;
    const int t = blockIdx.x, bl = blockIdx.y;
    const int l4 = t * 1024 + tid * 4;
    float4 sv[4];
    #pragma unroll
    for (int c = 0; c < 4; ++c)
        sv[c] = *(const float4*)&s2[((size_t)bl * 4 + c) * LEN + l4];
    #pragma unroll
    for (int o = 0; o < 40; ++o) {
        const float w0 = w_expand[o * 4 + 0], w1 = w_expand[o * 4 + 1];
        const float w2 = w_expand[o * 4 + 2], w3 = w_expand[o * 4 + 3];
        const float be = b_expand[o];
        ushort4* yp = (ushort4*)&y[((size_t)bl * 40 + o) * LEN + l4];
        ushort4 yv = *yp;
        float g0 = be + w0 * sv[0].x + w1 * sv[1].x + w2 * sv[2].x + w3 * sv[3].x;
        float g1 = be + w0 * sv[0].y + w1 * sv[1].y + w2 * sv[2].y + w3 * sv[3].y;
        float g2 = be + w0 * sv[0].z + w1 * sv[1].z + w2 * sv[2].z + w3 * sv[3].z;
        float g3 = be + w0 * sv[0].w + w1 * sv[1].w + w2 * sv[2].w + w3 * sv[3].w;
        bf16 h;
        h = __float2bfloat16(__bfloat162float(*(bf16*)&yv.x) / (1.f + __expf(-g0))); yv.x = *(unsigned short*)&h;
        h = __float2bfloat16(__bfloat162float(*(bf16*)&yv.y) / (1.f + __expf(-g1))); yv.y = *(unsigned short*)&h;
        h = __float2bfloat16(__bfloat162float(*(bf16*)&yv.z) / (1.f + __expf(-g2))); yv.z = *(unsigned short*)&h;
        h = __float2bfloat16(__bfloat162float(*(bf16*)&yv.w) / (1.f + __expf(-g3))); yv.w = *(unsigned short*)&h;
        *yp = yv;
    }
}

// ============ Kernel 4: effect conv (40->2, K=601, pad 300) + sigmoid, valid slice only ============
// out l' = l-500, l' in [0,64536). grid (64, nb), block 256, 4 consecutive l per thread (tile 1024).
// Channels in 10 chunks of 4; LDS data interleaved [p&3][c][p>>2] so the inner
// b32 reads are lane-stride-1 (conflict-free).
#define T4 408 // -> 1632 staged positions
__global__ __launch_bounds__(256) void k_effect(const bf16* __restrict__ mact,
        const float* __restrict__ w_eff, const float* __restrict__ b_eff,
        float* __restrict__ out, int b0) {
    __shared__ float xs[4][4][T4];                   // [p&3][c][p>>2]
    __shared__ __align__(16) float wse[2][4 * 604];  // k padded 601->604
    const int tid = threadIdx.x;
    const int t = blockIdx.x, bl = blockIdx.y;
    const int bg = b0 + bl;
    const int g0 = t * 1024 + 200;  // first staged position (always >= 200)

    float acc0[4] = {0.f, 0.f, 0.f, 0.f};
    float acc1[4] = {0.f, 0.f, 0.f, 0.f};

    for (int cc = 0; cc < 10; ++cc) {
        __syncthreads();
        for (int i = tid; i < 2 * 4 * 604; i += 256) {
            int k = i % 604, oc = i / 604;
            int o = oc >> 2, cl = oc & 3;
            wse[o][cl * 604 + k] = (k < 601) ? w_eff[(o * 40 + cc * 4 + cl) * 601 + k] : 0.f;
        }
        for (int p = tid; p < 1632; p += 256) {
            int g = g0 + p;
            bool ok = (g < LEN);
            #pragma unroll
            for (int c = 0; c < 4; ++c)
                xs[p & 3][c][p >> 2] = ok ? b2f(mact[((size_t)bl * 40 + cc * 4 + c) * LEN + g]) : 0.f;
        }
        __syncthreads();

        for (int c = 0; c < 4; ++c) {
            for (int k0 = 0; k0 < 604; k0 += 4) {
                const int q = k0 >> 2;
                float xv[7];
                xv[0] = xs[0][c][tid + q];
                xv[1] = xs[1][c][tid + q];
                xv[2] = xs[2][c][tid + q];
                xv[3] = xs[3][c][tid + q];
                xv[4] = xs[0][c][tid + q + 1];
                xv[5] = xs[1][c][tid + q + 1];
                xv[6] = xs[2][c][tid + q + 1];
                const float4 w0 = *(const float4*)&wse[0][c * 604 + k0];
                const float4 w1 = *(const float4*)&wse[1][c * 604 + k0];
                #pragma unroll
                for (int j = 0; j < 4; ++j) {
                    acc0[j] += w0.x * xv[j] + w0.y * xv[j + 1] + w0.z * xv[j + 2] + w0.w * xv[j + 3];
                    acc1[j] += w1.x * xv[j] + w1.y * xv[j + 1] + w1.z * xv[j + 2] + w1.w * xv[j + 3];
                }
            }
        }
    }

    const float bb0 = b_eff[0], bb1 = b_eff[1];
    #pragma unroll
    for (int j = 0; j < 4; ++j) {
        int lp = t * 1024 + tid * 4 + j;
        if (lp < LOUT) {
            out[((size_t)bg * 2 + 0) * LOUT + lp] = 1.f / (1.f + __expf(-(acc0[j] + bb0)));
            out[((size_t)bg * 2 + 1) * LOUT + lp] = 1.f / (1.f + __expf(-(acc1[j] + bb1)));
        }
    }
}

extern "C" void kernel_launch(void* const* d_in, const int* in_sizes, int n_in,
                              void* d_out, int out_size, void* d_ws, size_t ws_size,
                              hipStream_t stream) {
    const float* x        = (const float*)d_in[0];
    const float* w_motif  = (const float*)d_in[1];
    const float* b_motif  = (const float*)d_in[2];
    const float* w_reduce = (const float*)d_in[3];
    const float* b_reduce = (const float*)d_in[4];
    const float* w_fft    = (const float*)d_in[5];
    const float* b_fft    = (const float*)d_in[6];
    const float* w_expand = (const float*)d_in[7];
    const float* b_expand = (const float*)d_in[8];
    const float* w_eff    = (const float*)d_in[9];
    const float* b_eff    = (const float*)d_in[10];
    float* out = (float*)d_out;

    // per-batch workspace: y bf16 [40*LEN] + s1,s2 f32 [4*LEN] each
    const size_t PB_Y = (size_t)40 * LEN * sizeof(bf16);   // 5,242,880 B
    const size_t PB_S = (size_t)4 * LEN * sizeof(float);   // 1,048,576 B
    const size_t PERB = PB_Y + 2 * PB_S;                   // 7,340,032 B
    int nb = (int)(ws_size / PERB);
    if (nb > 32) nb = 32;
    if (nb < 1) nb = 1;

    char* base = (char*)d_ws;
    bf16*  y  = (bf16*)base;
    float* s1 = (float*)(base + PB_Y * (size_t)nb);
    float* s2 = (float*)(base + (PB_Y + PB_S) * (size_t)nb);

    for (int b0 = 0; b0 < 32; b0 += nb) {
        int nbb = (32 - b0 < nb) ? (32 - b0) : nb;
        hipLaunchKernelGGL(k_motif, dim3(128, nbb), dim3(256), 0, stream,
                           x, w_motif, b_motif, w_reduce, b_reduce, y, s1, b0);
        hipLaunchKernelGGL(k_fft, dim3(64, nbb), dim3(256), 0, stream, s1, w_fft, b_fft, s2);
        hipLaunchKernelGGL(k_gate, dim3(64, nbb), dim3(256), 0, stream, s2, w_expand, b_expand, y);
        hipLaunchKernelGGL(k_effect, dim3(64, nbb), dim3(256), 0, stream, y, w_eff, b_eff, out, b0);
    }
}

// Round 3
// 2257.516 us; speedup vs baseline: 2.7287x; 2.7287x over previous
//
#include <hip/hip_runtime.h>
#include <hip/hip_bf16.h>
#include <math.h>

#define LEN 65536
#define LOUT 64536
typedef __hip_bfloat16 bf16;
typedef __attribute__((ext_vector_type(8))) short short8;
typedef __attribute__((ext_vector_type(4))) float f32x4;

__device__ inline float b2f(bf16 h) { return __bfloat162float(h); }
__device__ inline bf16 f2b(float f) { return __float2bfloat16(f); }

// ============ Kernel 1: motif conv (4->40, K=51, pad25) + softplus + reduce(40->4) ============
__global__ __launch_bounds__(256) void k_motif(const float* __restrict__ x,
        const float* __restrict__ w_motif, const float* __restrict__ b_motif,
        const float* __restrict__ w_reduce, const float* __restrict__ b_reduce,
        bf16* __restrict__ y, float* __restrict__ s1, int b0) {
    __shared__ float xs[4][564];
    __shared__ __align__(16) float wsm[40 * 4 * 52];
    __shared__ float wred[160];
    const int tid = threadIdx.x;
    const int t = blockIdx.x, bl = blockIdx.y;
    const int bg = b0 + bl;
    const int l0 = t * 512;

    for (int i = tid; i < 40 * 4 * 52; i += 256) {
        int k = i % 52, oc = i / 52;
        wsm[i] = (k < 51) ? w_motif[oc * 51 + k] : 0.f;
    }
    for (int i = tid; i < 160; i += 256) wred[i] = w_reduce[i];
    for (int p = tid; p < 564; p += 256) {
        int g = l0 - 25 + p;
        bool ok = (g >= 0 && g < LEN);
        #pragma unroll
        for (int c = 0; c < 4; ++c)
            xs[c][p] = ok ? x[((size_t)bg * 4 + c) * LEN + g] : 0.f;
    }
    __syncthreads();

    float acc[40][2];
    #pragma unroll
    for (int o = 0; o < 40; ++o) { acc[o][0] = 0.f; acc[o][1] = 0.f; }

    for (int c = 0; c < 4; ++c) {
        for (int k0 = 0; k0 < 52; k0 += 4) {
            float xv[2][4];
            #pragma unroll
            for (int j = 0; j < 2; ++j)
                #pragma unroll
                for (int dk = 0; dk < 4; ++dk)
                    xv[j][dk] = xs[c][tid + j * 256 + k0 + dk];
            #pragma unroll
            for (int o = 0; o < 40; ++o) {
                const float4 wv = *(const float4*)&wsm[(o * 4 + c) * 52 + k0];
                #pragma unroll
                for (int j = 0; j < 2; ++j)
                    acc[o][j] += wv.x * xv[j][0] + wv.y * xv[j][1]
                               + wv.z * xv[j][2] + wv.w * xv[j][3];
            }
        }
    }

    #pragma unroll
    for (int j = 0; j < 2; ++j) {
        const int l = l0 + tid + j * 256;
        float s[4] = {0.f, 0.f, 0.f, 0.f};
        #pragma unroll
        for (int o = 0; o < 40; ++o) {
            float v = acc[o][j] + b_motif[o];
            float yv = (v > 20.f) ? v : log1pf(__expf(v));
            y[((size_t)bl * 40 + o) * LEN + l] = f2b(yv);
            #pragma unroll
            for (int c = 0; c < 4; ++c) s[c] += wred[c * 40 + o] * yv;
        }
        #pragma unroll
        for (int c = 0; c < 4; ++c)
            s1[((size_t)bl * 4 + c) * LEN + l] = s[c] + b_reduce[c];
    }
}

// ============ Kernel 2: fft conv (4->4, K=401, pad 200) ============
__global__ __launch_bounds__(256) void k_fft(const float* __restrict__ s1,
        const float* __restrict__ w_fft, const float* __restrict__ b_fft,
        float* __restrict__ s2) {
    __shared__ float xs[4][1428];
    __shared__ __align__(16) float wsf[4 * 4 * 404];
    const int tid = threadIdx.x;
    const int t = blockIdx.x, bl = blockIdx.y;
    const int l0 = t * 1024;

    for (int i = tid; i < 4 * 4 * 404; i += 256) {
        int k = i % 404, oc = i / 404;
        wsf[i] = (k < 401) ? w_fft[oc * 401 + k] : 0.f;
    }
    for (int p = tid; p < 1428; p += 256) {
        int g = l0 - 200 + p;
        bool ok = (g >= 0 && g < LEN);
        #pragma unroll
        for (int c = 0; c < 4; ++c)
            xs[c][p] = ok ? s1[((size_t)bl * 4 + c) * LEN + g] : 0.f;
    }
    __syncthreads();

    float acc[4][4];
    #pragma unroll
    for (int o = 0; o < 4; ++o)
        #pragma unroll
        for (int j = 0; j < 4; ++j) acc[o][j] = 0.f;

    for (int c = 0; c < 4; ++c) {
        for (int k0 = 0; k0 < 404; k0 += 4) {
            float xv[4][4];
            #pragma unroll
            for (int j = 0; j < 4; ++j)
                #pragma unroll
                for (int dk = 0; dk < 4; ++dk)
                    xv[j][dk] = xs[c][tid + j * 256 + k0 + dk];
            #pragma unroll
            for (int o = 0; o < 4; ++o) {
                const float4 wv = *(const float4*)&wsf[(o * 4 + c) * 404 + k0];
                #pragma unroll
                for (int j = 0; j < 4; ++j)
                    acc[o][j] += wv.x * xv[j][0] + wv.y * xv[j][1]
                               + wv.z * xv[j][2] + wv.w * xv[j][3];
            }
        }
    }

    #pragma unroll
    for (int o = 0; o < 4; ++o) {
        float bb = b_fft[o];
        #pragma unroll
        for (int j = 0; j < 4; ++j)
            s2[((size_t)bl * 4 + o) * LEN + l0 + tid + j * 256] = acc[o][j] + bb;
    }
}

// ============ Kernel 3: expand (4->40, 1x1) + sigmoid gate, in-place over y ============
__global__ __launch_bounds__(256) void k_gate(const float* __restrict__ s2,
        const float* __restrict__ w_expand, const float* __restrict__ b_expand,
        bf16* __restrict__ y) {
    const int tid = threadIdx.x;
    const int t = blockIdx.x, bl = blockIdx.y;
    const int l4 = t * 1024 + tid * 4;
    float4 sv[4];
    #pragma unroll
    for (int c = 0; c < 4; ++c)
        sv[c] = *(const float4*)&s2[((size_t)bl * 4 + c) * LEN + l4];
    #pragma unroll
    for (int o = 0; o < 40; ++o) {
        const float w0 = w_expand[o * 4 + 0], w1 = w_expand[o * 4 + 1];
        const float w2 = w_expand[o * 4 + 2], w3 = w_expand[o * 4 + 3];
        const float be = b_expand[o];
        ushort4* yp = (ushort4*)&y[((size_t)bl * 40 + o) * LEN + l4];
        ushort4 yv = *yp;
        float g0 = be + w0 * sv[0].x + w1 * sv[1].x + w2 * sv[2].x + w3 * sv[3].x;
        float g1 = be + w0 * sv[0].y + w1 * sv[1].y + w2 * sv[2].y + w3 * sv[3].y;
        float g2 = be + w0 * sv[0].z + w1 * sv[1].z + w2 * sv[2].z + w3 * sv[3].z;
        float g3 = be + w0 * sv[0].w + w1 * sv[1].w + w2 * sv[2].w + w3 * sv[3].w;
        bf16 h;
        h = __float2bfloat16(__bfloat162float(*(bf16*)&yv.x) / (1.f + __expf(-g0))); yv.x = *(unsigned short*)&h;
        h = __float2bfloat16(__bfloat162float(*(bf16*)&yv.y) / (1.f + __expf(-g1))); yv.y = *(unsigned short*)&h;
        h = __float2bfloat16(__bfloat162float(*(bf16*)&yv.z) / (1.f + __expf(-g2))); yv.z = *(unsigned short*)&h;
        h = __float2bfloat16(__bfloat162float(*(bf16*)&yv.w) / (1.f + __expf(-g3))); yv.w = *(unsigned short*)&h;
        *yp = yv;
    }
}

// ============ Kernel 4a: prep effect-conv A-fragments (weights, shift trick) ============
// A[(o,delta)][(c,k')] = w_eff[o][c][k'-delta], delta in [0,16), k' in [0,640).
// Fragment layout for mfma_f32_16x16x32_bf16 A-operand:
//   row = lane&15 (= delta), k = 8*(lane>>4)+i  (i = elem in short8)
// Buffer: [c40][qb4][Mt2][ql5][lane64][i8] bf16 -> 1,638,400 B
__global__ __launch_bounds__(256) void k_prep(const float* __restrict__ w_eff,
                                              short* __restrict__ fragA) {
    int idx = blockIdx.x * 256 + threadIdx.x;
    if (idx >= 40 * 4 * 2 * 5 * 64 * 8) return;
    int i = idx & 7;
    int lane = (idx >> 3) & 63;
    int rest = idx >> 9;
    int ql = rest % 5; rest /= 5;
    int Mt = rest & 1; rest >>= 1;
    int qb = rest & 3; int c = rest >> 2;
    int q = qb * 5 + ql;
    int dlt = lane & 15, kb = lane >> 4;
    int kp = 32 * q + 8 * kb + i;
    int kk = kp - dlt;
    float v = (kk >= 0 && kk < 601) ? w_eff[(Mt * 40 + c) * 601 + kk] : 0.f;
    bf16 h = __float2bfloat16(v);
    fragA[idx] = *(short*)&h;
}

// ============ Kernel 4b: effect conv (40->2, K=601) via bf16 MFMA + sigmoid ============
// Shift-GEMM: D[delta][n] = out[o=Mt][L0 + 256*tt + 16n + delta].
// B[(c,k'),n] = mact[c][L0+200 + 256*tt + 16n + k'] from XOR-swizzled linear LDS window.
// WG: 4096 positions, 4 waves x 4 tiles, 10 channel-chunks of 4. LDS 37.9 KB.
#define EFF_BLKS 592   // 16B blocks per channel window (4736 elems)
__global__ __launch_bounds__(256) void k_effect(const short* __restrict__ mact,
        const short* __restrict__ fragA, const float* __restrict__ b_eff,
        float* __restrict__ out, int b0) {
    __shared__ short bwin[4][EFF_BLKS * 8];
    const int tid = threadIdx.x;
    const int lane = tid & 63, wv = tid >> 6;
    const int wgl = blockIdx.x, bl = blockIdx.y, bg = b0 + bl;
    const int L0 = wgl * 4096;
    const int win0 = L0 + 200;          // multiple of 8 -> 16B-aligned vector loads
    const int ln15 = lane & 15, lkb = lane >> 4;

    f32x4 acc[2][4];
    #pragma unroll
    for (int Mt = 0; Mt < 2; ++Mt)
        #pragma unroll
        for (int nt = 0; nt < 4; ++nt)
            acc[Mt][nt] = (f32x4){0.f, 0.f, 0.f, 0.f};

    #pragma unroll 1
    for (int cc = 0; cc < 10; ++cc) {
        __syncthreads();
        // ---- stage 4 channels: global -> reg -> swizzled LDS ----
        #pragma unroll 1
        for (int cl = 0; cl < 4; ++cl) {
            const short* src = mact + ((size_t)bl * 40 + cc * 4 + cl) * LEN;
            for (int Lb = tid; Lb < EFF_BLKS; Lb += 256) {
                int gi = win0 + Lb * 8;
                short8 v;
                if (gi + 8 <= LEN) {
                    v = *(const short8*)(src + gi);
                } else {
                    #pragma unroll
                    for (int j = 0; j < 8; ++j)
                        v[j] = (gi + j < LEN) ? src[gi + j] : (short)0;
                }
                int Pb = Lb ^ ((Lb >> 3) & 7);
                *(short8*)(&bwin[cl][Pb * 8]) = v;
            }
        }
        __syncthreads();
        // ---- compute ----
        #pragma unroll 1
        for (int cl = 0; cl < 4; ++cl) {
            const int cg = cc * 4 + cl;
            #pragma unroll 1
            for (int qb = 0; qb < 4; ++qb) {
                short8 af[2][5];
                #pragma unroll
                for (int Mt = 0; Mt < 2; ++Mt)
                    #pragma unroll
                    for (int ql = 0; ql < 5; ++ql)
                        af[Mt][ql] = *(const short8*)(fragA +
                            (size_t)(((((cg * 4 + qb) * 2 + Mt) * 5 + ql) * 64 + lane) * 8));
                #pragma unroll
                for (int nt = 0; nt < 4; ++nt) {
                    const int tt = wv * 4 + nt;
                    #pragma unroll
                    for (int ql = 0; ql < 5; ++ql) {
                        int q = qb * 5 + ql;
                        int L = 2 * ln15 + lkb + 4 * q + 32 * tt;
                        int P = L ^ ((L >> 3) & 7);
                        short8 bfr = *(const short8*)(&bwin[cl][P * 8]);
                        acc[0][nt] = __builtin_amdgcn_mfma_f32_16x16x32_bf16(
                            af[0][ql], bfr, acc[0][nt], 0, 0, 0);
                        acc[1][nt] = __builtin_amdgcn_mfma_f32_16x16x32_bf16(
                            af[1][ql], bfr, acc[1][nt], 0, 0, 0);
                    }
                }
            }
        }
    }

    // ---- epilogue: bias + sigmoid, float4 stores (pos = L0+256tt+16n+4kb+j) ----
    const float be[2] = {b_eff[0], b_eff[1]};
    #pragma unroll
    for (int Mt = 0; Mt < 2; ++Mt) {
        #pragma unroll
        for (int nt = 0; nt < 4; ++nt) {
            int tt = wv * 4 + nt;
            int pos = L0 + tt * 256 + 16 * ln15 + 4 * lkb;
            if (pos < LOUT) {
                float4 st;
                st.x = 1.f / (1.f + __expf(-(acc[Mt][nt][0] + be[Mt])));
                st.y = 1.f / (1.f + __expf(-(acc[Mt][nt][1] + be[Mt])));
                st.z = 1.f / (1.f + __expf(-(acc[Mt][nt][2] + be[Mt])));
                st.w = 1.f / (1.f + __expf(-(acc[Mt][nt][3] + be[Mt])));
                *(float4*)(&out[((size_t)bg * 2 + Mt) * LOUT + pos]) = st;
            }
        }
    }
}

extern "C" void kernel_launch(void* const* d_in, const int* in_sizes, int n_in,
                              void* d_out, int out_size, void* d_ws, size_t ws_size,
                              hipStream_t stream) {
    const float* x        = (const float*)d_in[0];
    const float* w_motif  = (const float*)d_in[1];
    const float* b_motif  = (const float*)d_in[2];
    const float* w_reduce = (const float*)d_in[3];
    const float* b_reduce = (const float*)d_in[4];
    const float* w_fft    = (const float*)d_in[5];
    const float* b_fft    = (const float*)d_in[6];
    const float* w_expand = (const float*)d_in[7];
    const float* b_expand = (const float*)d_in[8];
    const float* w_eff    = (const float*)d_in[9];
    const float* b_eff    = (const float*)d_in[10];
    float* out = (float*)d_out;

    const size_t FRAGA_B = (size_t)40 * 4 * 2 * 5 * 64 * 8 * sizeof(short); // 1,638,400
    short* fragA = (short*)d_ws;
    char* rest = (char*)d_ws + FRAGA_B;

    const size_t PB_Y = (size_t)40 * LEN * sizeof(bf16);   // 5,242,880
    const size_t PB_S = (size_t)4 * LEN * sizeof(float);   // 1,048,576
    const size_t PERB = PB_Y + 2 * PB_S;                   // 7,340,032
    size_t avail = (ws_size > FRAGA_B) ? (ws_size - FRAGA_B) : 0;
    int nb = (int)(avail / PERB);
    if (nb > 32) nb = 32;
    if (nb < 1) nb = 1;

    bf16*  y  = (bf16*)rest;
    float* s1 = (float*)(rest + PB_Y * (size_t)nb);
    float* s2 = (float*)(rest + (PB_Y + PB_S) * (size_t)nb);

    hipLaunchKernelGGL(k_prep, dim3(3200), dim3(256), 0, stream, w_eff, fragA);

    for (int b0 = 0; b0 < 32; b0 += nb) {
        int nbb = (32 - b0 < nb) ? (32 - b0) : nb;
        hipLaunchKernelGGL(k_motif, dim3(128, nbb), dim3(256), 0, stream,
                           x, w_motif, b_motif, w_reduce, b_reduce, y, s1, b0);
        hipLaunchKernelGGL(k_fft, dim3(64, nbb), dim3(256), 0, stream, s1, w_fft, b_fft, s2);
        hipLaunchKernelGGL(k_gate, dim3(64, nbb), dim3(256), 0, stream, s2, w_expand, b_expand, y);
        hipLaunchKernelGGL(k_effect, dim3(16, nbb), dim3(256), 0, stream,
                           (const short*)y, fragA, b_eff, out, b0);
    }
}

// Round 4
// 1088.637 us; speedup vs baseline: 5.6585x; 2.0737x over previous
//
#include <hip/hip_runtime.h>
#include <hip/hip_bf16.h>
#include <math.h>

#define LEN 65536
#define LOUT 64536
typedef __hip_bfloat16 bf16;
typedef __attribute__((ext_vector_type(8))) short short8;
typedef __attribute__((ext_vector_type(4))) float f32x4;

__device__ inline float b2f(bf16 h) { return __bfloat162float(h); }
__device__ inline bf16 f2b(float f) { return __float2bfloat16(f); }
__device__ inline float us2f(unsigned short u) { bf16 h = *(bf16*)&u; return __bfloat162float(h); }

// ============ prep: pad motif weights to [40][4][52] (16B-aligned rows, uniform s_load) ============
__global__ __launch_bounds__(256) void k_prep_w(const float* __restrict__ w_motif,
                                                float* __restrict__ wpad) {
    int idx = blockIdx.x * 256 + threadIdx.x;
    if (idx >= 40 * 4 * 52) return;
    int k = idx % 52, oc = idx / 52;
    wpad[idx] = (k < 51) ? w_motif[oc * 51 + k] : 0.f;
}

// ============ Kernel 1: motif conv (4->40, K=51, pad25) + softplus + reduce(40->4) ============
// Weights via wave-uniform global reads -> SGPR/constant-cache. LDS only for x window (9KB).
__global__ __launch_bounds__(256) void k_motif(const float* __restrict__ x,
        const float* __restrict__ wpad, const float* __restrict__ b_motif,
        const float* __restrict__ w_reduce, const float* __restrict__ b_reduce,
        bf16* __restrict__ y, bf16* __restrict__ s1, int b0) {
    __shared__ float xs[4][564];                 // tile 512 + halo 52
    const int tid = threadIdx.x;
    const int t = blockIdx.x, bl = blockIdx.y;
    const int bg = b0 + bl;
    const int l0 = t * 512;

    for (int p = tid; p < 564; p += 256) {
        int g = l0 - 25 + p;
        bool ok = (g >= 0 && g < LEN);
        #pragma unroll
        for (int c = 0; c < 4; ++c)
            xs[c][p] = ok ? x[((size_t)bg * 4 + c) * LEN + g] : 0.f;
    }
    __syncthreads();

    float acc[40][2];
    #pragma unroll
    for (int o = 0; o < 40; ++o) { acc[o][0] = 0.f; acc[o][1] = 0.f; }

    #pragma unroll 1
    for (int c = 0; c < 4; ++c) {
        #pragma unroll 1
        for (int k0 = 0; k0 < 52; k0 += 4) {
            float xv[2][4];
            #pragma unroll
            for (int j = 0; j < 2; ++j)
                #pragma unroll
                for (int dk = 0; dk < 4; ++dk)
                    xv[j][dk] = xs[c][tid + j * 256 + k0 + dk];
            #pragma unroll
            for (int o = 0; o < 40; ++o) {
                const float4 wv = *(const float4*)&wpad[(o * 4 + c) * 52 + k0]; // uniform -> SGPR
                #pragma unroll
                for (int j = 0; j < 2; ++j)
                    acc[o][j] += wv.x * xv[j][0] + wv.y * xv[j][1]
                               + wv.z * xv[j][2] + wv.w * xv[j][3];
            }
        }
    }

    #pragma unroll
    for (int j = 0; j < 2; ++j) {
        const int l = l0 + tid + j * 256;
        float s[4] = {0.f, 0.f, 0.f, 0.f};
        #pragma unroll
        for (int o = 0; o < 40; ++o) {
            float v = acc[o][j] + b_motif[o];
            float yv = (v > 20.f) ? v : log1pf(__expf(v));   // softplus
            y[((size_t)bl * 40 + o) * LEN + l] = f2b(yv);
            #pragma unroll
            for (int c = 0; c < 4; ++c) s[c] += w_reduce[c * 40 + o] * yv;
        }
        #pragma unroll
        for (int c = 0; c < 4; ++c)
            s1[((size_t)bl * 4 + c) * LEN + l] = f2b(s[c] + b_reduce[c]);
    }
}

// ============ prep: fft-conv A-fragments (shift trick, 16 shifts) ============
// A[(o,delta)][(c,kk')] = w_fft[o][c][kk'-delta], kk' in [0,448). o=Mt (4 tiles).
// layout: [c4][qb7][Mt4][ql2][lane64][i8] bf16 -> 229,376 B
__global__ __launch_bounds__(256) void k_prep_fft(const float* __restrict__ w_fft,
                                                  short* __restrict__ fragA) {
    int idx = blockIdx.x * 256 + threadIdx.x;
    if (idx >= 4 * 7 * 4 * 2 * 64 * 8) return;
    int i = idx & 7;
    int lane = (idx >> 3) & 63;
    int rest = idx >> 9;
    int ql = rest & 1; rest >>= 1;
    int Mt = rest & 3; rest >>= 2;
    int qb = rest % 7; int c = rest / 7;
    int dlt = lane & 15, kb = lane >> 4;
    int kkp = 32 * (qb * 2 + ql) + 8 * kb + i;
    int kk = kkp - dlt;
    float v = (kk >= 0 && kk < 401) ? w_fft[(Mt * 4 + c) * 401 + kk] : 0.f;
    bf16 h = f2b(v);
    fragA[idx] = *(short*)&h;
}

// ============ Kernel 2: fft conv (4->4, K=401, pad 200) via bf16 MFMA ============
// Same shift-GEMM pattern as k_effect: D[(o,delta)][n] = s2[o][P0+16n+delta].
// WG: 4096 positions, 4 waves x 4 nt-tiles, 4 M-tiles (o), K = 4c x 448.
#define FFT_BLKS 568
__global__ __launch_bounds__(256) void k_fft(const short* __restrict__ s1,
        const short* __restrict__ fragA, const float* __restrict__ b_fft,
        bf16* __restrict__ s2) {
    __shared__ __align__(16) short bwin[4][FFT_BLKS * 8];   // 36,352 B
    const int tid = threadIdx.x;
    const int lane = tid & 63, wv = tid >> 6;
    const int wg = blockIdx.x, bl = blockIdx.y;
    const int P0 = wg * 4096;
    const int win0 = P0 - 200;
    const int ln15 = lane & 15, lkb = lane >> 4;

    f32x4 acc[4][4]; // [Mt=o][nt]
    #pragma unroll
    for (int Mt = 0; Mt < 4; ++Mt)
        #pragma unroll
        for (int nt = 0; nt < 4; ++nt)
            acc[Mt][nt] = (f32x4){0.f, 0.f, 0.f, 0.f};

    // stage 4 channels of s1 into swizzled LDS window
    #pragma unroll 1
    for (int cl = 0; cl < 4; ++cl) {
        const short* src = s1 + ((size_t)bl * 4 + cl) * LEN;
        for (int Lb = tid; Lb < FFT_BLKS; Lb += 256) {
            int gi = win0 + Lb * 8;
            short8 v;
            if (gi >= 0 && gi + 8 <= LEN) {
                v = *(const short8*)(src + gi);
            } else {
                #pragma unroll
                for (int j = 0; j < 8; ++j)
                    v[j] = (gi + j >= 0 && gi + j < LEN) ? src[gi + j] : (short)0;
            }
            int Pb = Lb ^ ((Lb >> 3) & 7);
            *(short8*)(&bwin[cl][Pb * 8]) = v;
        }
    }
    __syncthreads();

    #pragma unroll 1
    for (int cl = 0; cl < 4; ++cl) {
        #pragma unroll 1
        for (int qb = 0; qb < 7; ++qb) {
            short8 af[4][2];
            #pragma unroll
            for (int Mt = 0; Mt < 4; ++Mt)
                #pragma unroll
                for (int ql = 0; ql < 2; ++ql)
                    af[Mt][ql] = *(const short8*)(fragA +
                        (size_t)((((cl * 7 + qb) * 4 + Mt) * 2 + ql) * 64 + lane) * 8);
            #pragma unroll
            for (int nt = 0; nt < 4; ++nt) {
                const int tt = wv * 4 + nt;
                #pragma unroll
                for (int ql = 0; ql < 2; ++ql) {
                    int qc = qb * 2 + ql;
                    int L = 2 * ln15 + lkb + 4 * qc + 32 * tt;
                    int P = L ^ ((L >> 3) & 7);
                    short8 bfr = *(const short8*)(&bwin[cl][P * 8]);
                    #pragma unroll
                    for (int Mt = 0; Mt < 4; ++Mt)
                        acc[Mt][nt] = __builtin_amdgcn_mfma_f32_16x16x32_bf16(
                            af[Mt][ql], bfr, acc[Mt][nt], 0, 0, 0);
                }
            }
        }
    }

    // epilogue: bias, store bf16 (pos = P0 + 256*tt + 16*ln15 + 4*lkb + j)
    #pragma unroll
    for (int Mt = 0; Mt < 4; ++Mt) {
        float bb = b_fft[Mt];
        #pragma unroll
        for (int nt = 0; nt < 4; ++nt) {
            int tt = wv * 4 + nt;
            int pos = P0 + tt * 256 + 16 * ln15 + 4 * lkb;
            ushort4 st;
            bf16 h;
            h = f2b(acc[Mt][nt][0] + bb); st.x = *(unsigned short*)&h;
            h = f2b(acc[Mt][nt][1] + bb); st.y = *(unsigned short*)&h;
            h = f2b(acc[Mt][nt][2] + bb); st.z = *(unsigned short*)&h;
            h = f2b(acc[Mt][nt][3] + bb); st.w = *(unsigned short*)&h;
            *(ushort4*)(&s2[((size_t)bl * 4 + Mt) * LEN + pos]) = st;
        }
    }
}

// ============ Kernel 3: expand (4->40, 1x1) + sigmoid gate, in-place over y ============
__global__ __launch_bounds__(256) void k_gate(const unsigned short* __restrict__ s2,
        const float* __restrict__ w_expand, const float* __restrict__ b_expand,
        bf16* __restrict__ y) {
    const int tid = threadIdx.x;
    const int t = blockIdx.x, bl = blockIdx.y;
    const int l4 = t * 1024 + tid * 4;
    float sv[4][4];
    #pragma unroll
    for (int c = 0; c < 4; ++c) {
        ushort4 v = *(const ushort4*)&s2[((size_t)bl * 4 + c) * LEN + l4];
        sv[c][0] = us2f(v.x); sv[c][1] = us2f(v.y); sv[c][2] = us2f(v.z); sv[c][3] = us2f(v.w);
    }
    #pragma unroll
    for (int o = 0; o < 40; ++o) {
        const float w0 = w_expand[o * 4 + 0], w1 = w_expand[o * 4 + 1];
        const float w2 = w_expand[o * 4 + 2], w3 = w_expand[o * 4 + 3];
        const float be = b_expand[o];
        ushort4* yp = (ushort4*)&y[((size_t)bl * 40 + o) * LEN + l4];
        ushort4 yv = *yp;
        float g0 = be + w0 * sv[0][0] + w1 * sv[1][0] + w2 * sv[2][0] + w3 * sv[3][0];
        float g1 = be + w0 * sv[0][1] + w1 * sv[1][1] + w2 * sv[2][1] + w3 * sv[3][1];
        float g2 = be + w0 * sv[0][2] + w1 * sv[1][2] + w2 * sv[2][2] + w3 * sv[3][2];
        float g3 = be + w0 * sv[0][3] + w1 * sv[1][3] + w2 * sv[2][3] + w3 * sv[3][3];
        bf16 h;
        h = f2b(us2f(yv.x) / (1.f + __expf(-g0))); yv.x = *(unsigned short*)&h;
        h = f2b(us2f(yv.y) / (1.f + __expf(-g1))); yv.y = *(unsigned short*)&h;
        h = f2b(us2f(yv.z) / (1.f + __expf(-g2))); yv.z = *(unsigned short*)&h;
        h = f2b(us2f(yv.w) / (1.f + __expf(-g3))); yv.w = *(unsigned short*)&h;
        *yp = yv;
    }
}

// ============ prep: effect-conv A-fragments ============
__global__ __launch_bounds__(256) void k_prep(const float* __restrict__ w_eff,
                                              short* __restrict__ fragA) {
    int idx = blockIdx.x * 256 + threadIdx.x;
    if (idx >= 40 * 4 * 2 * 5 * 64 * 8) return;
    int i = idx & 7;
    int lane = (idx >> 3) & 63;
    int rest = idx >> 9;
    int ql = rest % 5; rest /= 5;
    int Mt = rest & 1; rest >>= 1;
    int qb = rest & 3; int c = rest >> 2;
    int q = qb * 5 + ql;
    int dlt = lane & 15, kb = lane >> 4;
    int kp = 32 * q + 8 * kb + i;
    int kk = kp - dlt;
    float v = (kk >= 0 && kk < 601) ? w_eff[(Mt * 40 + c) * 601 + kk] : 0.f;
    bf16 h = __float2bfloat16(v);
    fragA[idx] = *(short*)&h;
}

// ============ Kernel 4: effect conv (40->2, K=601) via bf16 MFMA + sigmoid ============
#define EFF_BLKS 592
__global__ __launch_bounds__(256) void k_effect(const short* __restrict__ mact,
        const short* __restrict__ fragA, const float* __restrict__ b_eff,
        float* __restrict__ out, int b0) {
    __shared__ __align__(16) short bwin[4][EFF_BLKS * 8];
    const int tid = threadIdx.x;
    const int lane = tid & 63, wv = tid >> 6;
    const int wgl = blockIdx.x, bl = blockIdx.y, bg = b0 + bl;
    const int L0 = wgl * 4096;
    const int win0 = L0 + 200;
    const int ln15 = lane & 15, lkb = lane >> 4;

    f32x4 acc[2][4];
    #pragma unroll
    for (int Mt = 0; Mt < 2; ++Mt)
        #pragma unroll
        for (int nt = 0; nt < 4; ++nt)
            acc[Mt][nt] = (f32x4){0.f, 0.f, 0.f, 0.f};

    #pragma unroll 1
    for (int cc = 0; cc < 10; ++cc) {
        __syncthreads();
        #pragma unroll 1
        for (int cl = 0; cl < 4; ++cl) {
            const short* src = mact + ((size_t)bl * 40 + cc * 4 + cl) * LEN;
            for (int Lb = tid; Lb < EFF_BLKS; Lb += 256) {
                int gi = win0 + Lb * 8;
                short8 v;
                if (gi + 8 <= LEN) {
                    v = *(const short8*)(src + gi);
                } else {
                    #pragma unroll
                    for (int j = 0; j < 8; ++j)
                        v[j] = (gi + j < LEN) ? src[gi + j] : (short)0;
                }
                int Pb = Lb ^ ((Lb >> 3) & 7);
                *(short8*)(&bwin[cl][Pb * 8]) = v;
            }
        }
        __syncthreads();
        #pragma unroll 1
        for (int cl = 0; cl < 4; ++cl) {
            const int cg = cc * 4 + cl;
            #pragma unroll 1
            for (int qb = 0; qb < 4; ++qb) {
                short8 af[2][5];
                #pragma unroll
                for (int Mt = 0; Mt < 2; ++Mt)
                    #pragma unroll
                    for (int ql = 0; ql < 5; ++ql)
                        af[Mt][ql] = *(const short8*)(fragA +
                            (size_t)(((((cg * 4 + qb) * 2 + Mt) * 5 + ql) * 64 + lane) * 8));
                #pragma unroll
                for (int nt = 0; nt < 4; ++nt) {
                    const int tt = wv * 4 + nt;
                    #pragma unroll
                    for (int ql = 0; ql < 5; ++ql) {
                        int q = qb * 5 + ql;
                        int L = 2 * ln15 + lkb + 4 * q + 32 * tt;
                        int P = L ^ ((L >> 3) & 7);
                        short8 bfr = *(const short8*)(&bwin[cl][P * 8]);
                        acc[0][nt] = __builtin_amdgcn_mfma_f32_16x16x32_bf16(
                            af[0][ql], bfr, acc[0][nt], 0, 0, 0);
                        acc[1][nt] = __builtin_amdgcn_mfma_f32_16x16x32_bf16(
                            af[1][ql], bfr, acc[1][nt], 0, 0, 0);
                    }
                }
            }
        }
    }

    const float be[2] = {b_eff[0], b_eff[1]};
    #pragma unroll
    for (int Mt = 0; Mt < 2; ++Mt) {
        #pragma unroll
        for (int nt = 0; nt < 4; ++nt) {
            int tt = wv * 4 + nt;
            int pos = L0 + tt * 256 + 16 * ln15 + 4 * lkb;
            if (pos < LOUT) {
                float4 st;
                st.x = 1.f / (1.f + __expf(-(acc[Mt][nt][0] + be[Mt])));
                st.y = 1.f / (1.f + __expf(-(acc[Mt][nt][1] + be[Mt])));
                st.z = 1.f / (1.f + __expf(-(acc[Mt][nt][2] + be[Mt])));
                st.w = 1.f / (1.f + __expf(-(acc[Mt][nt][3] + be[Mt])));
                *(float4*)(&out[((size_t)bg * 2 + Mt) * LOUT + pos]) = st;
            }
        }
    }
}

extern "C" void kernel_launch(void* const* d_in, const int* in_sizes, int n_in,
                              void* d_out, int out_size, void* d_ws, size_t ws_size,
                              hipStream_t stream) {
    const float* x        = (const float*)d_in[0];
    const float* w_motif  = (const float*)d_in[1];
    const float* b_motif  = (const float*)d_in[2];
    const float* w_reduce = (const float*)d_in[3];
    const float* b_reduce = (const float*)d_in[4];
    const float* w_fft    = (const float*)d_in[5];
    const float* b_fft    = (const float*)d_in[6];
    const float* w_expand = (const float*)d_in[7];
    const float* b_expand = (const float*)d_in[8];
    const float* w_eff    = (const float*)d_in[9];
    const float* b_eff    = (const float*)d_in[10];
    float* out = (float*)d_out;

    const size_t FRAGA_EFF = (size_t)40 * 4 * 2 * 5 * 64 * 8 * 2;  // 1,638,400
    const size_t FRAGA_FFT = (size_t)4 * 7 * 4 * 2 * 64 * 8 * 2;   //   229,376
    const size_t WPAD_B    = (size_t)40 * 4 * 52 * 4;              //    33,280
    const size_t HEAD = FRAGA_EFF + FRAGA_FFT + WPAD_B;            // 1,901,056

    short* fragA_eff = (short*)d_ws;
    short* fragA_fft = (short*)((char*)d_ws + FRAGA_EFF);
    float* wpad      = (float*)((char*)d_ws + FRAGA_EFF + FRAGA_FFT);
    char*  rest      = (char*)d_ws + HEAD;

    const size_t PB_Y = (size_t)40 * LEN * 2;   // y bf16: 5,242,880
    const size_t PB_S = (size_t)4 * LEN * 2;    // s1/s2 bf16: 524,288 each
    const size_t PERB = PB_Y + 2 * PB_S;        // 6,291,456
    size_t avail = (ws_size > HEAD) ? (ws_size - HEAD) : 0;
    int nb = (int)(avail / PERB);
    if (nb > 32) nb = 32;
    if (nb < 1) nb = 1;

    bf16* y  = (bf16*)rest;
    bf16* s1 = (bf16*)(rest + PB_Y * (size_t)nb);
    bf16* s2 = (bf16*)(rest + (PB_Y + PB_S) * (size_t)nb);

    hipLaunchKernelGGL(k_prep,     dim3(3200), dim3(256), 0, stream, w_eff, fragA_eff);
    hipLaunchKernelGGL(k_prep_fft, dim3(448),  dim3(256), 0, stream, w_fft, fragA_fft);
    hipLaunchKernelGGL(k_prep_w,   dim3(33),   dim3(256), 0, stream, w_motif, wpad);

    for (int b0 = 0; b0 < 32; b0 += nb) {
        int nbb = (32 - b0 < nb) ? (32 - b0) : nb;
        hipLaunchKernelGGL(k_motif, dim3(128, nbb), dim3(256), 0, stream,
                           x, wpad, b_motif, w_reduce, b_reduce, y, s1, b0);
        hipLaunchKernelGGL(k_fft, dim3(16, nbb), dim3(256), 0, stream,
                           (const short*)s1, fragA_fft, b_fft, s2);
        hipLaunchKernelGGL(k_gate, dim3(64, nbb), dim3(256), 0, stream,
                           (const unsigned short*)s2, w_expand, b_expand, y);
        hipLaunchKernelGGL(k_effect, dim3(16, nbb), dim3(256), 0, stream,
                           (const short*)y, fragA_eff, b_eff, out, b0);
    }
}

// Round 5
// 704.440 us; speedup vs baseline: 8.7446x; 1.5454x over previous
//
#include <hip/hip_runtime.h>
#include <hip/hip_bf16.h>
#include <math.h>

#define LEN 65536
#define LOUT 64536
typedef __hip_bfloat16 bf16;
typedef __attribute__((ext_vector_type(8))) short short8;
typedef __attribute__((ext_vector_type(4))) float f32x4;

__device__ inline float b2f(bf16 h) { return __bfloat162float(h); }
__device__ inline bf16 f2b(float f) { return __float2bfloat16(f); }
__device__ inline float us2f(unsigned short u) { bf16 h = *(bf16*)&u; return __bfloat162float(h); }

// ============ prep: motif-conv A-fragments (shift trick + align-shift 7) ============
// A[(o,delta)][(c,m)] = w_motif[o][c][m-7-delta], m in [0,96) (3 kfrags/channel).
// layout: [o40][c4][qc3][lane64][i8] bf16 -> 491,520 B
__global__ __launch_bounds__(256) void k_prep_mot(const float* __restrict__ w_motif,
                                                  short* __restrict__ fragA) {
    int idx = blockIdx.x * 256 + threadIdx.x;
    if (idx >= 40 * 4 * 3 * 64 * 8) return;
    int i = idx & 7;
    int lane = (idx >> 3) & 63;
    int rest = idx >> 9;
    int qc = rest % 3; rest /= 3;
    int c = rest & 3; int o = rest >> 2;
    int dlt = lane & 15, kb = lane >> 4;
    int m = 32 * qc + 8 * kb + i;
    int k = m - 7 - dlt;
    float v = (k >= 0 && k < 51) ? w_motif[(o * 4 + c) * 51 + k] : 0.f;
    bf16 h = f2b(v);
    fragA[idx] = *(short*)&h;
}

// ============ Kernel 1: motif conv (4->40, K=51, pad25) + softplus via bf16 MFMA ============
// blockIdx.z = o-group (4 outputs). Per WG 4096 positions, 4 waves x 4 nt.
// B[(c,m)][n] = x_bf16[c][L0-32 + 16n + m]  (x idx = pos-25+k, k=m-7-delta).
#define MOT_BLKS 522
#define MOT_PAD  528
__global__ __launch_bounds__(256, 2) void k_motif_mfma(const float* __restrict__ x,
        const short* __restrict__ fragA, const float* __restrict__ b_motif,
        bf16* __restrict__ y, int b0) {
    __shared__ __align__(16) short bwin[4][MOT_PAD * 8];   // 33,792 B
    const int tid = threadIdx.x;
    const int lane = tid & 63, wv = tid >> 6;
    const int wg = blockIdx.x, bl = blockIdx.y, og = blockIdx.z;
    const int bg = b0 + bl;
    const int L0 = wg * 4096;
    const int win0 = L0 - 32;
    const int ln15 = lane & 15, lkb = lane >> 4;

    // A-frags resident in VGPRs: 4 Mt x 12 kfrags (192 VGPR)
    short8 af[4][12];
    #pragma unroll
    for (int Mt = 0; Mt < 4; ++Mt)
        #pragma unroll
        for (int kq = 0; kq < 12; ++kq)
            af[Mt][kq] = *(const short8*)(fragA +
                (size_t)(((og * 4 + Mt) * 12 + kq) * 64 + lane) * 8);

    // stage x window fp32 -> bf16 into swizzled LDS
    #pragma unroll 1
    for (int c = 0; c < 4; ++c) {
        const float* src = x + ((size_t)bg * 4 + c) * LEN;
        for (int Lb = tid; Lb < MOT_BLKS; Lb += 256) {
            int gi = win0 + Lb * 8;
            short8 v;
            if (gi >= 0 && gi + 8 <= LEN) {
                float4 f0 = *(const float4*)(src + gi);
                float4 f1 = *(const float4*)(src + gi + 4);
                bf16 h;
                h = f2b(f0.x); v[0] = *(short*)&h;
                h = f2b(f0.y); v[1] = *(short*)&h;
                h = f2b(f0.z); v[2] = *(short*)&h;
                h = f2b(f0.w); v[3] = *(short*)&h;
                h = f2b(f1.x); v[4] = *(short*)&h;
                h = f2b(f1.y); v[5] = *(short*)&h;
                h = f2b(f1.z); v[6] = *(short*)&h;
                h = f2b(f1.w); v[7] = *(short*)&h;
            } else {
                #pragma unroll
                for (int j = 0; j < 8; ++j) {
                    float fv = (gi + j >= 0 && gi + j < LEN) ? src[gi + j] : 0.f;
                    bf16 h = f2b(fv);
                    v[j] = *(short*)&h;
                }
            }
            int Pb = Lb ^ ((Lb >> 3) & 7);
            *(short8*)(&bwin[c][Pb * 8]) = v;
        }
    }
    __syncthreads();

    #pragma unroll 1
    for (int nt = 0; nt < 4; ++nt) {
        const int tt = wv * 4 + nt;
        f32x4 acc[4];
        #pragma unroll
        for (int Mt = 0; Mt < 4; ++Mt) acc[Mt] = (f32x4){0.f, 0.f, 0.f, 0.f};
        #pragma unroll
        for (int c = 0; c < 4; ++c) {
            #pragma unroll
            for (int qc = 0; qc < 3; ++qc) {
                int L = 32 * tt + 2 * ln15 + 4 * qc + lkb;
                int P = L ^ ((L >> 3) & 7);
                short8 bfr = *(const short8*)(&bwin[c][P * 8]);
                #pragma unroll
                for (int Mt = 0; Mt < 4; ++Mt)
                    acc[Mt] = __builtin_amdgcn_mfma_f32_16x16x32_bf16(
                        af[Mt][c * 3 + qc], bfr, acc[Mt], 0, 0, 0);
            }
        }
        // epilogue: bias + softplus, bf16 store (pos = L0+256tt+16ln15+4lkb+j)
        #pragma unroll
        for (int Mt = 0; Mt < 4; ++Mt) {
            float bb = b_motif[og * 4 + Mt];
            int pos = L0 + tt * 256 + 16 * ln15 + 4 * lkb;
            ushort4 st; bf16 h;
            float v0 = acc[Mt][0] + bb, v1 = acc[Mt][1] + bb;
            float v2 = acc[Mt][2] + bb, v3 = acc[Mt][3] + bb;
            v0 = (v0 > 20.f) ? v0 : log1pf(__expf(v0));
            v1 = (v1 > 20.f) ? v1 : log1pf(__expf(v1));
            v2 = (v2 > 20.f) ? v2 : log1pf(__expf(v2));
            v3 = (v3 > 20.f) ? v3 : log1pf(__expf(v3));
            h = f2b(v0); st.x = *(unsigned short*)&h;
            h = f2b(v1); st.y = *(unsigned short*)&h;
            h = f2b(v2); st.z = *(unsigned short*)&h;
            h = f2b(v3); st.w = *(unsigned short*)&h;
            *(ushort4*)(&y[((size_t)bl * 40 + og * 4 + Mt) * LEN + pos]) = st;
        }
    }
}

// ============ Kernel 1b: reduce (40->4, 1x1) from y, memory-bound pass ============
__global__ __launch_bounds__(256) void k_reduce(const short* __restrict__ y,
        const float* __restrict__ w_reduce, const float* __restrict__ b_reduce,
        bf16* __restrict__ s1) {
    const int tid = threadIdx.x;
    const int bl = blockIdx.y;
    const int l8 = (blockIdx.x * 256 + tid) * 8;
    float s[4][8];
    #pragma unroll
    for (int c = 0; c < 4; ++c)
        #pragma unroll
        for (int e = 0; e < 8; ++e) s[c][e] = b_reduce[c];
    #pragma unroll 1
    for (int o = 0; o < 40; ++o) {
        short8 v = *(const short8*)(y + ((size_t)bl * 40 + o) * LEN + l8);
        float yv[8];
        #pragma unroll
        for (int e = 0; e < 8; ++e) yv[e] = us2f((unsigned short)v[e]);
        #pragma unroll
        for (int c = 0; c < 4; ++c) {
            float w = w_reduce[c * 40 + o];
            #pragma unroll
            for (int e = 0; e < 8; ++e) s[c][e] += w * yv[e];
        }
    }
    #pragma unroll
    for (int c = 0; c < 4; ++c) {
        short8 st; bf16 h;
        #pragma unroll
        for (int e = 0; e < 8; ++e) { h = f2b(s[c][e]); st[e] = *(short*)&h; }
        *(short8*)(&s1[((size_t)bl * 4 + c) * LEN + l8]) = st;
    }
}

// ============ prep: fft-conv A-fragments ============
__global__ __launch_bounds__(256) void k_prep_fft(const float* __restrict__ w_fft,
                                                  short* __restrict__ fragA) {
    int idx = blockIdx.x * 256 + threadIdx.x;
    if (idx >= 4 * 7 * 4 * 2 * 64 * 8) return;
    int i = idx & 7;
    int lane = (idx >> 3) & 63;
    int rest = idx >> 9;
    int ql = rest & 1; rest >>= 1;
    int Mt = rest & 3; rest >>= 2;
    int qb = rest % 7; int c = rest / 7;
    int dlt = lane & 15, kb = lane >> 4;
    int kkp = 32 * (qb * 2 + ql) + 8 * kb + i;
    int kk = kkp - dlt;
    float v = (kk >= 0 && kk < 401) ? w_fft[(Mt * 4 + c) * 401 + kk] : 0.f;
    bf16 h = f2b(v);
    fragA[idx] = *(short*)&h;
}

// ============ Kernel 2: fft conv (4->4, K=401, pad 200) via bf16 MFMA ============
#define FFT_BLKS 568
__global__ __launch_bounds__(256) void k_fft(const short* __restrict__ s1,
        const short* __restrict__ fragA, const float* __restrict__ b_fft,
        bf16* __restrict__ s2) {
    __shared__ __align__(16) short bwin[4][FFT_BLKS * 8];   // 36,352 B
    const int tid = threadIdx.x;
    const int lane = tid & 63, wv = tid >> 6;
    const int wg = blockIdx.x, bl = blockIdx.y;
    const int P0 = wg * 4096;
    const int win0 = P0 - 200;
    const int ln15 = lane & 15, lkb = lane >> 4;

    f32x4 acc[4][4];
    #pragma unroll
    for (int Mt = 0; Mt < 4; ++Mt)
        #pragma unroll
        for (int nt = 0; nt < 4; ++nt)
            acc[Mt][nt] = (f32x4){0.f, 0.f, 0.f, 0.f};

    #pragma unroll 1
    for (int cl = 0; cl < 4; ++cl) {
        const short* src = s1 + ((size_t)bl * 4 + cl) * LEN;
        for (int Lb = tid; Lb < FFT_BLKS; Lb += 256) {
            int gi = win0 + Lb * 8;
            short8 v;
            if (gi >= 0 && gi + 8 <= LEN) {
                v = *(const short8*)(src + gi);
            } else {
                #pragma unroll
                for (int j = 0; j < 8; ++j)
                    v[j] = (gi + j >= 0 && gi + j < LEN) ? src[gi + j] : (short)0;
            }
            int Pb = Lb ^ ((Lb >> 3) & 7);
            *(short8*)(&bwin[cl][Pb * 8]) = v;
        }
    }
    __syncthreads();

    #pragma unroll 1
    for (int cl = 0; cl < 4; ++cl) {
        #pragma unroll 1
        for (int qb = 0; qb < 7; ++qb) {
            short8 af[4][2];
            #pragma unroll
            for (int Mt = 0; Mt < 4; ++Mt)
                #pragma unroll
                for (int ql = 0; ql < 2; ++ql)
                    af[Mt][ql] = *(const short8*)(fragA +
                        (size_t)((((cl * 7 + qb) * 4 + Mt) * 2 + ql) * 64 + lane) * 8);
            #pragma unroll
            for (int nt = 0; nt < 4; ++nt) {
                const int tt = wv * 4 + nt;
                #pragma unroll
                for (int ql = 0; ql < 2; ++ql) {
                    int qc = qb * 2 + ql;
                    int L = 2 * ln15 + lkb + 4 * qc + 32 * tt;
                    int P = L ^ ((L >> 3) & 7);
                    short8 bfr = *(const short8*)(&bwin[cl][P * 8]);
                    #pragma unroll
                    for (int Mt = 0; Mt < 4; ++Mt)
                        acc[Mt][nt] = __builtin_amdgcn_mfma_f32_16x16x32_bf16(
                            af[Mt][ql], bfr, acc[Mt][nt], 0, 0, 0);
                }
            }
        }
    }

    #pragma unroll
    for (int Mt = 0; Mt < 4; ++Mt) {
        float bb = b_fft[Mt];
        #pragma unroll
        for (int nt = 0; nt < 4; ++nt) {
            int tt = wv * 4 + nt;
            int pos = P0 + tt * 256 + 16 * ln15 + 4 * lkb;
            ushort4 st; bf16 h;
            h = f2b(acc[Mt][nt][0] + bb); st.x = *(unsigned short*)&h;
            h = f2b(acc[Mt][nt][1] + bb); st.y = *(unsigned short*)&h;
            h = f2b(acc[Mt][nt][2] + bb); st.z = *(unsigned short*)&h;
            h = f2b(acc[Mt][nt][3] + bb); st.w = *(unsigned short*)&h;
            *(ushort4*)(&s2[((size_t)bl * 4 + Mt) * LEN + pos]) = st;
        }
    }
}

// ============ Kernel 3: expand (4->40, 1x1) + sigmoid gate, in-place over y ============
__global__ __launch_bounds__(256) void k_gate(const unsigned short* __restrict__ s2,
        const float* __restrict__ w_expand, const float* __restrict__ b_expand,
        bf16* __restrict__ y) {
    const int tid = threadIdx.x;
    const int t = blockIdx.x, bl = blockIdx.y;
    const int l4 = t * 1024 + tid * 4;
    float sv[4][4];
    #pragma unroll
    for (int c = 0; c < 4; ++c) {
        ushort4 v = *(const ushort4*)&s2[((size_t)bl * 4 + c) * LEN + l4];
        sv[c][0] = us2f(v.x); sv[c][1] = us2f(v.y); sv[c][2] = us2f(v.z); sv[c][3] = us2f(v.w);
    }
    #pragma unroll
    for (int o = 0; o < 40; ++o) {
        const float w0 = w_expand[o * 4 + 0], w1 = w_expand[o * 4 + 1];
        const float w2 = w_expand[o * 4 + 2], w3 = w_expand[o * 4 + 3];
        const float be = b_expand[o];
        ushort4* yp = (ushort4*)&y[((size_t)bl * 40 + o) * LEN + l4];
        ushort4 yv = *yp;
        float g0 = be + w0 * sv[0][0] + w1 * sv[1][0] + w2 * sv[2][0] + w3 * sv[3][0];
        float g1 = be + w0 * sv[0][1] + w1 * sv[1][1] + w2 * sv[2][1] + w3 * sv[3][1];
        float g2 = be + w0 * sv[0][2] + w1 * sv[1][2] + w2 * sv[2][2] + w3 * sv[3][2];
        float g3 = be + w0 * sv[0][3] + w1 * sv[1][3] + w2 * sv[2][3] + w3 * sv[3][3];
        bf16 h;
        h = f2b(us2f(yv.x) / (1.f + __expf(-g0))); yv.x = *(unsigned short*)&h;
        h = f2b(us2f(yv.y) / (1.f + __expf(-g1))); yv.y = *(unsigned short*)&h;
        h = f2b(us2f(yv.z) / (1.f + __expf(-g2))); yv.z = *(unsigned short*)&h;
        h = f2b(us2f(yv.w) / (1.f + __expf(-g3))); yv.w = *(unsigned short*)&h;
        *yp = yv;
    }
}

// ============ prep: effect-conv A-fragments ============
__global__ __launch_bounds__(256) void k_prep(const float* __restrict__ w_eff,
                                              short* __restrict__ fragA) {
    int idx = blockIdx.x * 256 + threadIdx.x;
    if (idx >= 40 * 4 * 2 * 5 * 64 * 8) return;
    int i = idx & 7;
    int lane = (idx >> 3) & 63;
    int rest = idx >> 9;
    int ql = rest % 5; rest /= 5;
    int Mt = rest & 1; rest >>= 1;
    int qb = rest & 3; int c = rest >> 2;
    int q = qb * 5 + ql;
    int dlt = lane & 15, kb = lane >> 4;
    int kp = 32 * q + 8 * kb + i;
    int kk = kp - dlt;
    float v = (kk >= 0 && kk < 601) ? w_eff[(Mt * 40 + c) * 601 + kk] : 0.f;
    bf16 h = __float2bfloat16(v);
    fragA[idx] = *(short*)&h;
}

// ============ Kernel 4: effect conv (40->2, K=601) via bf16 MFMA + sigmoid ============
#define EFF_BLKS 592
__global__ __launch_bounds__(256) void k_effect(const short* __restrict__ mact,
        const short* __restrict__ fragA, const float* __restrict__ b_eff,
        float* __restrict__ out, int b0) {
    __shared__ __align__(16) short bwin[4][EFF_BLKS * 8];
    const int tid = threadIdx.x;
    const int lane = tid & 63, wv = tid >> 6;
    const int wgl = blockIdx.x, bl = blockIdx.y, bg = b0 + bl;
    const int L0 = wgl * 4096;
    const int win0 = L0 + 200;
    const int ln15 = lane & 15, lkb = lane >> 4;

    f32x4 acc[2][4];
    #pragma unroll
    for (int Mt = 0; Mt < 2; ++Mt)
        #pragma unroll
        for (int nt = 0; nt < 4; ++nt)
            acc[Mt][nt] = (f32x4){0.f, 0.f, 0.f, 0.f};

    #pragma unroll 1
    for (int cc = 0; cc < 10; ++cc) {
        __syncthreads();
        #pragma unroll 1
        for (int cl = 0; cl < 4; ++cl) {
            const short* src = mact + ((size_t)bl * 40 + cc * 4 + cl) * LEN;
            for (int Lb = tid; Lb < EFF_BLKS; Lb += 256) {
                int gi = win0 + Lb * 8;
                short8 v;
                if (gi + 8 <= LEN) {
                    v = *(const short8*)(src + gi);
                } else {
                    #pragma unroll
                    for (int j = 0; j < 8; ++j)
                        v[j] = (gi + j < LEN) ? src[gi + j] : (short)0;
                }
                int Pb = Lb ^ ((Lb >> 3) & 7);
                *(short8*)(&bwin[cl][Pb * 8]) = v;
            }
        }
        __syncthreads();
        #pragma unroll 1
        for (int cl = 0; cl < 4; ++cl) {
            const int cg = cc * 4 + cl;
            #pragma unroll 1
            for (int qb = 0; qb < 4; ++qb) {
                short8 af[2][5];
                #pragma unroll
                for (int Mt = 0; Mt < 2; ++Mt)
                    #pragma unroll
                    for (int ql = 0; ql < 5; ++ql)
                        af[Mt][ql] = *(const short8*)(fragA +
                            (size_t)(((((cg * 4 + qb) * 2 + Mt) * 5 + ql) * 64 + lane) * 8));
                #pragma unroll
                for (int nt = 0; nt < 4; ++nt) {
                    const int tt = wv * 4 + nt;
                    #pragma unroll
                    for (int ql = 0; ql < 5; ++ql) {
                        int q = qb * 5 + ql;
                        int L = 2 * ln15 + lkb + 4 * q + 32 * tt;
                        int P = L ^ ((L >> 3) & 7);
                        short8 bfr = *(const short8*)(&bwin[cl][P * 8]);
                        acc[0][nt] = __builtin_amdgcn_mfma_f32_16x16x32_bf16(
                            af[0][ql], bfr, acc[0][nt], 0, 0, 0);
                        acc[1][nt] = __builtin_amdgcn_mfma_f32_16x16x32_bf16(
                            af[1][ql], bfr, acc[1][nt], 0, 0, 0);
                    }
                }
            }
        }
    }

    const float be[2] = {b_eff[0], b_eff[1]};
    #pragma unroll
    for (int Mt = 0; Mt < 2; ++Mt) {
        #pragma unroll
        for (int nt = 0; nt < 4; ++nt) {
            int tt = wv * 4 + nt;
            int pos = L0 + tt * 256 + 16 * ln15 + 4 * lkb;
            if (pos < LOUT) {
                float4 st;
                st.x = 1.f / (1.f + __expf(-(acc[Mt][nt][0] + be[Mt])));
                st.y = 1.f / (1.f + __expf(-(acc[Mt][nt][1] + be[Mt])));
                st.z = 1.f / (1.f + __expf(-(acc[Mt][nt][2] + be[Mt])));
                st.w = 1.f / (1.f + __expf(-(acc[Mt][nt][3] + be[Mt])));
                *(float4*)(&out[((size_t)bg * 2 + Mt) * LOUT + pos]) = st;
            }
        }
    }
}

extern "C" void kernel_launch(void* const* d_in, const int* in_sizes, int n_in,
                              void* d_out, int out_size, void* d_ws, size_t ws_size,
                              hipStream_t stream) {
    const float* x        = (const float*)d_in[0];
    const float* w_motif  = (const float*)d_in[1];
    const float* b_motif  = (const float*)d_in[2];
    const float* w_reduce = (const float*)d_in[3];
    const float* b_reduce = (const float*)d_in[4];
    const float* w_fft    = (const float*)d_in[5];
    const float* b_fft    = (const float*)d_in[6];
    const float* w_expand = (const float*)d_in[7];
    const float* b_expand = (const float*)d_in[8];
    const float* w_eff    = (const float*)d_in[9];
    const float* b_eff    = (const float*)d_in[10];
    float* out = (float*)d_out;

    const size_t FRAGA_EFF = (size_t)40 * 4 * 2 * 5 * 64 * 8 * 2;  // 1,638,400
    const size_t FRAGA_FFT = (size_t)4 * 7 * 4 * 2 * 64 * 8 * 2;   //   229,376
    const size_t FRAGA_MOT = (size_t)40 * 4 * 3 * 64 * 8 * 2;      //   491,520
    const size_t HEAD = FRAGA_EFF + FRAGA_FFT + FRAGA_MOT;         // 2,359,296

    short* fragA_eff = (short*)d_ws;
    short* fragA_fft = (short*)((char*)d_ws + FRAGA_EFF);
    short* fragA_mot = (short*)((char*)d_ws + FRAGA_EFF + FRAGA_FFT);
    char*  rest      = (char*)d_ws + HEAD;

    const size_t PB_Y = (size_t)40 * LEN * 2;   // y bf16: 5,242,880
    const size_t PB_S = (size_t)4 * LEN * 2;    // s1/s2 bf16: 524,288 each
    const size_t PERB = PB_Y + 2 * PB_S;        // 6,291,456
    size_t avail = (ws_size > HEAD) ? (ws_size - HEAD) : 0;
    int nb = (int)(avail / PERB);
    if (nb > 32) nb = 32;
    if (nb < 1) nb = 1;

    bf16* y  = (bf16*)rest;
    bf16* s1 = (bf16*)(rest + PB_Y * (size_t)nb);
    bf16* s2 = (bf16*)(rest + (PB_Y + PB_S) * (size_t)nb);

    hipLaunchKernelGGL(k_prep,     dim3(3200), dim3(256), 0, stream, w_eff, fragA_eff);
    hipLaunchKernelGGL(k_prep_fft, dim3(448),  dim3(256), 0, stream, w_fft, fragA_fft);
    hipLaunchKernelGGL(k_prep_mot, dim3(960),  dim3(256), 0, stream, w_motif, fragA_mot);

    for (int b0 = 0; b0 < 32; b0 += nb) {
        int nbb = (32 - b0 < nb) ? (32 - b0) : nb;
        hipLaunchKernelGGL(k_motif_mfma, dim3(16, nbb, 10), dim3(256), 0, stream,
                           x, fragA_mot, b_motif, y, b0);
        hipLaunchKernelGGL(k_reduce, dim3(32, nbb), dim3(256), 0, stream,
                           (const short*)y, w_reduce, b_reduce, s1);
        hipLaunchKernelGGL(k_fft, dim3(16, nbb), dim3(256), 0, stream,
                           (const short*)s1, fragA_fft, b_fft, s2);
        hipLaunchKernelGGL(k_gate, dim3(64, nbb), dim3(256), 0, stream,
                           (const unsigned short*)s2, w_expand, b_expand, y);
        hipLaunchKernelGGL(k_effect, dim3(16, nbb), dim3(256), 0, stream,
                           (const short*)y, fragA_eff, b_eff, out, b0);
    }
}

// Round 6
// 526.788 us; speedup vs baseline: 11.6936x; 1.3372x over previous
//
#include <hip/hip_runtime.h>
#include <hip/hip_bf16.h>
#include <math.h>

#define LEN 65536
#define LOUT 64536
typedef __hip_bfloat16 bf16;
typedef __attribute__((ext_vector_type(8))) short short8;
typedef __attribute__((ext_vector_type(4))) float f32x4;

__device__ inline float b2f(bf16 h) { return __bfloat162float(h); }
__device__ inline bf16 f2b(float f) { return __float2bfloat16(f); }
__device__ inline float us2f(unsigned short u) { bf16 h = *(bf16*)&u; return __bfloat162float(h); }
// cheap softplus: max(v,0) + log(1+exp(-|v|)), hw exp/log
__device__ inline float softplus_f(float v) {
    return fmaxf(v, 0.f) + __logf(1.f + __expf(-fabsf(v)));
}

// ============ Kernel 0: convert x fp32 -> bf16 (whole tensor, one pass) ============
__global__ __launch_bounds__(256) void k_x2b(const float* __restrict__ x,
                                             short* __restrict__ xb, int n8) {
    int i = blockIdx.x * 256 + threadIdx.x;
    if (i >= n8) return;
    const float* src = x + (size_t)i * 8;
    float4 f0 = *(const float4*)src;
    float4 f1 = *(const float4*)(src + 4);
    short8 v; bf16 h;
    h = f2b(f0.x); v[0] = *(short*)&h;
    h = f2b(f0.y); v[1] = *(short*)&h;
    h = f2b(f0.z); v[2] = *(short*)&h;
    h = f2b(f0.w); v[3] = *(short*)&h;
    h = f2b(f1.x); v[4] = *(short*)&h;
    h = f2b(f1.y); v[5] = *(short*)&h;
    h = f2b(f1.z); v[6] = *(short*)&h;
    h = f2b(f1.w); v[7] = *(short*)&h;
    *(short8*)(xb + (size_t)i * 8) = v;
}

// ============ prep: motif-conv A-fragments (shift trick + align-shift 7) ============
// A[(o,delta)][(c,m)] = w_motif[o][c][m-7-delta], m in [0,96).
// layout: [o40][c4][qc3][lane64][i8] bf16
__global__ __launch_bounds__(256) void k_prep_mot(const float* __restrict__ w_motif,
                                                  short* __restrict__ fragA) {
    int idx = blockIdx.x * 256 + threadIdx.x;
    if (idx >= 40 * 4 * 3 * 64 * 8) return;
    int i = idx & 7;
    int lane = (idx >> 3) & 63;
    int rest = idx >> 9;
    int qc = rest % 3; rest /= 3;
    int c = rest & 3; int o = rest >> 2;
    int dlt = lane & 15, kb = lane >> 4;
    int m = 32 * qc + 8 * kb + i;
    int k = m - 7 - dlt;
    float v = (k >= 0 && k < 51) ? w_motif[(o * 4 + c) * 51 + k] : 0.f;
    bf16 h = f2b(v);
    fragA[idx] = *(short*)&h;
}

// ============ Kernel 1: motif conv (4->40, K=51, pad25) + softplus via bf16 MFMA ============
// blockIdx.z = o-group (4 outputs). Per WG 4096 positions, 4 waves x 4 nt.
// B[(c,m)][n] = xb[c][L0-32 + 16n + m]; xb is bf16 (L2-resident across the 10 o-groups).
#define MOT_BLKS 522
#define MOT_PAD  528
__global__ __launch_bounds__(256, 2) void k_motif_mfma(const short* __restrict__ xb,
        const short* __restrict__ fragA, const float* __restrict__ b_motif,
        bf16* __restrict__ y, int b0) {
    __shared__ __align__(16) short bwin[4][MOT_PAD * 8];   // 33,792 B
    const int tid = threadIdx.x;
    const int lane = tid & 63, wv = tid >> 6;
    const int wg = blockIdx.x, bl = blockIdx.y, og = blockIdx.z;
    const int bg = b0 + bl;
    const int L0 = wg * 4096;
    const int win0 = L0 - 32;
    const int ln15 = lane & 15, lkb = lane >> 4;

    // A-frags resident in VGPRs: 4 Mt x 12 kfrags
    short8 af[4][12];
    #pragma unroll
    for (int Mt = 0; Mt < 4; ++Mt)
        #pragma unroll
        for (int kq = 0; kq < 12; ++kq)
            af[Mt][kq] = *(const short8*)(fragA +
                (size_t)(((og * 4 + Mt) * 12 + kq) * 64 + lane) * 8);

    // stage bf16 x window into swizzled LDS (pure copy)
    #pragma unroll 1
    for (int c = 0; c < 4; ++c) {
        const short* src = xb + ((size_t)bg * 4 + c) * LEN;
        for (int Lb = tid; Lb < MOT_BLKS; Lb += 256) {
            int gi = win0 + Lb * 8;
            short8 v;
            if (gi >= 0 && gi + 8 <= LEN) {
                v = *(const short8*)(src + gi);
            } else {
                #pragma unroll
                for (int j = 0; j < 8; ++j)
                    v[j] = (gi + j >= 0 && gi + j < LEN) ? src[gi + j] : (short)0;
            }
            int Pb = Lb ^ ((Lb >> 3) & 7);
            *(short8*)(&bwin[c][Pb * 8]) = v;
        }
    }
    __syncthreads();

    #pragma unroll 1
    for (int nt = 0; nt < 4; ++nt) {
        const int tt = wv * 4 + nt;
        f32x4 acc[4];
        #pragma unroll
        for (int Mt = 0; Mt < 4; ++Mt) acc[Mt] = (f32x4){0.f, 0.f, 0.f, 0.f};
        #pragma unroll
        for (int c = 0; c < 4; ++c) {
            #pragma unroll
            for (int qc = 0; qc < 3; ++qc) {
                int L = 32 * tt + 2 * ln15 + 4 * qc + lkb;
                int P = L ^ ((L >> 3) & 7);
                short8 bfr = *(const short8*)(&bwin[c][P * 8]);
                #pragma unroll
                for (int Mt = 0; Mt < 4; ++Mt)
                    acc[Mt] = __builtin_amdgcn_mfma_f32_16x16x32_bf16(
                        af[Mt][c * 3 + qc], bfr, acc[Mt], 0, 0, 0);
            }
        }
        // epilogue: bias + cheap softplus, bf16 store
        #pragma unroll
        for (int Mt = 0; Mt < 4; ++Mt) {
            float bb = b_motif[og * 4 + Mt];
            int pos = L0 + tt * 256 + 16 * ln15 + 4 * lkb;
            ushort4 st; bf16 h;
            float v0 = softplus_f(acc[Mt][0] + bb);
            float v1 = softplus_f(acc[Mt][1] + bb);
            float v2 = softplus_f(acc[Mt][2] + bb);
            float v3 = softplus_f(acc[Mt][3] + bb);
            h = f2b(v0); st.x = *(unsigned short*)&h;
            h = f2b(v1); st.y = *(unsigned short*)&h;
            h = f2b(v2); st.z = *(unsigned short*)&h;
            h = f2b(v3); st.w = *(unsigned short*)&h;
            *(ushort4*)(&y[((size_t)bl * 40 + og * 4 + Mt) * LEN + pos]) = st;
        }
    }
}

// ============ Kernel 1b: reduce (40->4, 1x1) from y, memory-bound pass ============
__global__ __launch_bounds__(256) void k_reduce(const short* __restrict__ y,
        const float* __restrict__ w_reduce, const float* __restrict__ b_reduce,
        bf16* __restrict__ s1) {
    const int tid = threadIdx.x;
    const int bl = blockIdx.y;
    const int l8 = (blockIdx.x * 256 + tid) * 8;
    float s[4][8];
    #pragma unroll
    for (int c = 0; c < 4; ++c)
        #pragma unroll
        for (int e = 0; e < 8; ++e) s[c][e] = b_reduce[c];
    #pragma unroll 1
    for (int o = 0; o < 40; ++o) {
        short8 v = *(const short8*)(y + ((size_t)bl * 40 + o) * LEN + l8);
        float yv[8];
        #pragma unroll
        for (int e = 0; e < 8; ++e) yv[e] = us2f((unsigned short)v[e]);
        #pragma unroll
        for (int c = 0; c < 4; ++c) {
            float w = w_reduce[c * 40 + o];
            #pragma unroll
            for (int e = 0; e < 8; ++e) s[c][e] += w * yv[e];
        }
    }
    #pragma unroll
    for (int c = 0; c < 4; ++c) {
        short8 st; bf16 h;
        #pragma unroll
        for (int e = 0; e < 8; ++e) { h = f2b(s[c][e]); st[e] = *(short*)&h; }
        *(short8*)(&s1[((size_t)bl * 4 + c) * LEN + l8]) = st;
    }
}

// ============ prep: fft-conv A-fragments ============
__global__ __launch_bounds__(256) void k_prep_fft(const float* __restrict__ w_fft,
                                                  short* __restrict__ fragA) {
    int idx = blockIdx.x * 256 + threadIdx.x;
    if (idx >= 4 * 7 * 4 * 2 * 64 * 8) return;
    int i = idx & 7;
    int lane = (idx >> 3) & 63;
    int rest = idx >> 9;
    int ql = rest & 1; rest >>= 1;
    int Mt = rest & 3; rest >>= 2;
    int qb = rest % 7; int c = rest / 7;
    int dlt = lane & 15, kb = lane >> 4;
    int kkp = 32 * (qb * 2 + ql) + 8 * kb + i;
    int kk = kkp - dlt;
    float v = (kk >= 0 && kk < 401) ? w_fft[(Mt * 4 + c) * 401 + kk] : 0.f;
    bf16 h = f2b(v);
    fragA[idx] = *(short*)&h;
}

// ============ Kernel 2: fft conv (4->4, K=401, pad 200) via bf16 MFMA ============
#define FFT_BLKS 568
__global__ __launch_bounds__(256) void k_fft(const short* __restrict__ s1,
        const short* __restrict__ fragA, const float* __restrict__ b_fft,
        bf16* __restrict__ s2) {
    __shared__ __align__(16) short bwin[4][FFT_BLKS * 8];   // 36,352 B
    const int tid = threadIdx.x;
    const int lane = tid & 63, wv = tid >> 6;
    const int wg = blockIdx.x, bl = blockIdx.y;
    const int P0 = wg * 4096;
    const int win0 = P0 - 200;
    const int ln15 = lane & 15, lkb = lane >> 4;

    f32x4 acc[4][4];
    #pragma unroll
    for (int Mt = 0; Mt < 4; ++Mt)
        #pragma unroll
        for (int nt = 0; nt < 4; ++nt)
            acc[Mt][nt] = (f32x4){0.f, 0.f, 0.f, 0.f};

    #pragma unroll 1
    for (int cl = 0; cl < 4; ++cl) {
        const short* src = s1 + ((size_t)bl * 4 + cl) * LEN;
        for (int Lb = tid; Lb < FFT_BLKS; Lb += 256) {
            int gi = win0 + Lb * 8;
            short8 v;
            if (gi >= 0 && gi + 8 <= LEN) {
                v = *(const short8*)(src + gi);
            } else {
                #pragma unroll
                for (int j = 0; j < 8; ++j)
                    v[j] = (gi + j >= 0 && gi + j < LEN) ? src[gi + j] : (short)0;
            }
            int Pb = Lb ^ ((Lb >> 3) & 7);
            *(short8*)(&bwin[cl][Pb * 8]) = v;
        }
    }
    __syncthreads();

    #pragma unroll 1
    for (int cl = 0; cl < 4; ++cl) {
        #pragma unroll 1
        for (int qb = 0; qb < 7; ++qb) {
            short8 af[4][2];
            #pragma unroll
            for (int Mt = 0; Mt < 4; ++Mt)
                #pragma unroll
                for (int ql = 0; ql < 2; ++ql)
                    af[Mt][ql] = *(const short8*)(fragA +
                        (size_t)((((cl * 7 + qb) * 4 + Mt) * 2 + ql) * 64 + lane) * 8);
            #pragma unroll
            for (int nt = 0; nt < 4; ++nt) {
                const int tt = wv * 4 + nt;
                #pragma unroll
                for (int ql = 0; ql < 2; ++ql) {
                    int qc = qb * 2 + ql;
                    int L = 2 * ln15 + lkb + 4 * qc + 32 * tt;
                    int P = L ^ ((L >> 3) & 7);
                    short8 bfr = *(const short8*)(&bwin[cl][P * 8]);
                    #pragma unroll
                    for (int Mt = 0; Mt < 4; ++Mt)
                        acc[Mt][nt] = __builtin_amdgcn_mfma_f32_16x16x32_bf16(
                            af[Mt][ql], bfr, acc[Mt][nt], 0, 0, 0);
                }
            }
        }
    }

    #pragma unroll
    for (int Mt = 0; Mt < 4; ++Mt) {
        float bb = b_fft[Mt];
        #pragma unroll
        for (int nt = 0; nt < 4; ++nt) {
            int tt = wv * 4 + nt;
            int pos = P0 + tt * 256 + 16 * ln15 + 4 * lkb;
            ushort4 st; bf16 h;
            h = f2b(acc[Mt][nt][0] + bb); st.x = *(unsigned short*)&h;
            h = f2b(acc[Mt][nt][1] + bb); st.y = *(unsigned short*)&h;
            h = f2b(acc[Mt][nt][2] + bb); st.z = *(unsigned short*)&h;
            h = f2b(acc[Mt][nt][3] + bb); st.w = *(unsigned short*)&h;
            *(ushort4*)(&s2[((size_t)bl * 4 + Mt) * LEN + pos]) = st;
        }
    }
}

// ============ Kernel 3: expand (4->40, 1x1) + sigmoid gate, in-place over y ============
__global__ __launch_bounds__(256) void k_gate(const unsigned short* __restrict__ s2,
        const float* __restrict__ w_expand, const float* __restrict__ b_expand,
        bf16* __restrict__ y) {
    const int tid = threadIdx.x;
    const int t = blockIdx.x, bl = blockIdx.y;
    const int l4 = t * 1024 + tid * 4;
    float sv[4][4];
    #pragma unroll
    for (int c = 0; c < 4; ++c) {
        ushort4 v = *(const ushort4*)&s2[((size_t)bl * 4 + c) * LEN + l4];
        sv[c][0] = us2f(v.x); sv[c][1] = us2f(v.y); sv[c][2] = us2f(v.z); sv[c][3] = us2f(v.w);
    }
    #pragma unroll
    for (int o = 0; o < 40; ++o) {
        const float w0 = w_expand[o * 4 + 0], w1 = w_expand[o * 4 + 1];
        const float w2 = w_expand[o * 4 + 2], w3 = w_expand[o * 4 + 3];
        const float be = b_expand[o];
        ushort4* yp = (ushort4*)&y[((size_t)bl * 40 + o) * LEN + l4];
        ushort4 yv = *yp;
        float g0 = be + w0 * sv[0][0] + w1 * sv[1][0] + w2 * sv[2][0] + w3 * sv[3][0];
        float g1 = be + w0 * sv[0][1] + w1 * sv[1][1] + w2 * sv[2][1] + w3 * sv[3][1];
        float g2 = be + w0 * sv[0][2] + w1 * sv[1][2] + w2 * sv[2][2] + w3 * sv[3][2];
        float g3 = be + w0 * sv[0][3] + w1 * sv[1][3] + w2 * sv[2][3] + w3 * sv[3][3];
        bf16 h;
        h = f2b(us2f(yv.x) / (1.f + __expf(-g0))); yv.x = *(unsigned short*)&h;
        h = f2b(us2f(yv.y) / (1.f + __expf(-g1))); yv.y = *(unsigned short*)&h;
        h = f2b(us2f(yv.z) / (1.f + __expf(-g2))); yv.z = *(unsigned short*)&h;
        h = f2b(us2f(yv.w) / (1.f + __expf(-g3))); yv.w = *(unsigned short*)&h;
        *yp = yv;
    }
}

// ============ prep: effect-conv A-fragments ============
__global__ __launch_bounds__(256) void k_prep(const float* __restrict__ w_eff,
                                              short* __restrict__ fragA) {
    int idx = blockIdx.x * 256 + threadIdx.x;
    if (idx >= 40 * 4 * 2 * 5 * 64 * 8) return;
    int i = idx & 7;
    int lane = (idx >> 3) & 63;
    int rest = idx >> 9;
    int ql = rest % 5; rest /= 5;
    int Mt = rest & 1; rest >>= 1;
    int qb = rest & 3; int c = rest >> 2;
    int q = qb * 5 + ql;
    int dlt = lane & 15, kb = lane >> 4;
    int kp = 32 * q + 8 * kb + i;
    int kk = kp - dlt;
    float v = (kk >= 0 && kk < 601) ? w_eff[(Mt * 40 + c) * 601 + kk] : 0.f;
    bf16 h = __float2bfloat16(v);
    fragA[idx] = *(short*)&h;
}

// ============ Kernel 4: effect conv (40->2, K=601) via bf16 MFMA + sigmoid ============
#define EFF_BLKS 592
__global__ __launch_bounds__(256) void k_effect(const short* __restrict__ mact,
        const short* __restrict__ fragA, const float* __restrict__ b_eff,
        float* __restrict__ out, int b0) {
    __shared__ __align__(16) short bwin[4][EFF_BLKS * 8];
    const int tid = threadIdx.x;
    const int lane = tid & 63, wv = tid >> 6;
    const int wgl = blockIdx.x, bl = blockIdx.y, bg = b0 + bl;
    const int L0 = wgl * 4096;
    const int win0 = L0 + 200;
    const int ln15 = lane & 15, lkb = lane >> 4;

    f32x4 acc[2][4];
    #pragma unroll
    for (int Mt = 0; Mt < 2; ++Mt)
        #pragma unroll
        for (int nt = 0; nt < 4; ++nt)
            acc[Mt][nt] = (f32x4){0.f, 0.f, 0.f, 0.f};

    #pragma unroll 1
    for (int cc = 0; cc < 10; ++cc) {
        __syncthreads();
        #pragma unroll 1
        for (int cl = 0; cl < 4; ++cl) {
            const short* src = mact + ((size_t)bl * 40 + cc * 4 + cl) * LEN;
            for (int Lb = tid; Lb < EFF_BLKS; Lb += 256) {
                int gi = win0 + Lb * 8;
                short8 v;
                if (gi + 8 <= LEN) {
                    v = *(const short8*)(src + gi);
                } else {
                    #pragma unroll
                    for (int j = 0; j < 8; ++j)
                        v[j] = (gi + j < LEN) ? src[gi + j] : (short)0;
                }
                int Pb = Lb ^ ((Lb >> 3) & 7);
                *(short8*)(&bwin[cl][Pb * 8]) = v;
            }
        }
        __syncthreads();
        #pragma unroll 1
        for (int cl = 0; cl < 4; ++cl) {
            const int cg = cc * 4 + cl;
            #pragma unroll 1
            for (int qb = 0; qb < 4; ++qb) {
                short8 af[2][5];
                #pragma unroll
                for (int Mt = 0; Mt < 2; ++Mt)
                    #pragma unroll
                    for (int ql = 0; ql < 5; ++ql)
                        af[Mt][ql] = *(const short8*)(fragA +
                            (size_t)(((((cg * 4 + qb) * 2 + Mt) * 5 + ql) * 64 + lane) * 8));
                #pragma unroll
                for (int nt = 0; nt < 4; ++nt) {
                    const int tt = wv * 4 + nt;
                    #pragma unroll
                    for (int ql = 0; ql < 5; ++ql) {
                        int q = qb * 5 + ql;
                        int L = 2 * ln15 + lkb + 4 * q + 32 * tt;
                        int P = L ^ ((L >> 3) & 7);
                        short8 bfr = *(const short8*)(&bwin[cl][P * 8]);
                        acc[0][nt] = __builtin_amdgcn_mfma_f32_16x16x32_bf16(
                            af[0][ql], bfr, acc[0][nt], 0, 0, 0);
                        acc[1][nt] = __builtin_amdgcn_mfma_f32_16x16x32_bf16(
                            af[1][ql], bfr, acc[1][nt], 0, 0, 0);
                    }
                }
            }
        }
    }

    const float be[2] = {b_eff[0], b_eff[1]};
    #pragma unroll
    for (int Mt = 0; Mt < 2; ++Mt) {
        #pragma unroll
        for (int nt = 0; nt < 4; ++nt) {
            int tt = wv * 4 + nt;
            int pos = L0 + tt * 256 + 16 * ln15 + 4 * lkb;
            if (pos < LOUT) {
                float4 st;
                st.x = 1.f / (1.f + __expf(-(acc[Mt][nt][0] + be[Mt])));
                st.y = 1.f / (1.f + __expf(-(acc[Mt][nt][1] + be[Mt])));
                st.z = 1.f / (1.f + __expf(-(acc[Mt][nt][2] + be[Mt])));
                st.w = 1.f / (1.f + __expf(-(acc[Mt][nt][3] + be[Mt])));
                *(float4*)(&out[((size_t)bg * 2 + Mt) * LOUT + pos]) = st;
            }
        }
    }
}

extern "C" void kernel_launch(void* const* d_in, const int* in_sizes, int n_in,
                              void* d_out, int out_size, void* d_ws, size_t ws_size,
                              hipStream_t stream) {
    const float* x        = (const float*)d_in[0];
    const float* w_motif  = (const float*)d_in[1];
    const float* b_motif  = (const float*)d_in[2];
    const float* w_reduce = (const float*)d_in[3];
    const float* b_reduce = (const float*)d_in[4];
    const float* w_fft    = (const float*)d_in[5];
    const float* b_fft    = (const float*)d_in[6];
    const float* w_expand = (const float*)d_in[7];
    const float* b_expand = (const float*)d_in[8];
    const float* w_eff    = (const float*)d_in[9];
    const float* b_eff    = (const float*)d_in[10];
    float* out = (float*)d_out;

    const size_t FRAGA_EFF = (size_t)40 * 4 * 2 * 5 * 64 * 8 * 2;  // 1,638,400
    const size_t FRAGA_FFT = (size_t)4 * 7 * 4 * 2 * 64 * 8 * 2;   //   229,376
    const size_t FRAGA_MOT = (size_t)40 * 4 * 3 * 64 * 8 * 2;      //   491,520
    const size_t XB_B      = (size_t)32 * 4 * LEN * 2;             // 16,777,216
    const size_t HEAD = FRAGA_EFF + FRAGA_FFT + FRAGA_MOT + XB_B;  // 19,136,512

    short* fragA_eff = (short*)d_ws;
    short* fragA_fft = (short*)((char*)d_ws + FRAGA_EFF);
    short* fragA_mot = (short*)((char*)d_ws + FRAGA_EFF + FRAGA_FFT);
    short* xb        = (short*)((char*)d_ws + FRAGA_EFF + FRAGA_FFT + FRAGA_MOT);
    char*  rest      = (char*)d_ws + HEAD;

    const size_t PB_Y = (size_t)40 * LEN * 2;   // y bf16: 5,242,880
    const size_t PB_S = (size_t)4 * LEN * 2;    // s1/s2 bf16: 524,288 each
    const size_t PERB = PB_Y + 2 * PB_S;        // 6,291,456
    size_t avail = (ws_size > HEAD) ? (ws_size - HEAD) : 0;
    int nb = (int)(avail / PERB);
    if (nb > 32) nb = 32;
    if (nb < 1) nb = 1;

    bf16* y  = (bf16*)rest;
    bf16* s1 = (bf16*)(rest + PB_Y * (size_t)nb);
    bf16* s2 = (bf16*)(rest + (PB_Y + PB_S) * (size_t)nb);

    hipLaunchKernelGGL(k_prep,     dim3(3200), dim3(256), 0, stream, w_eff, fragA_eff);
    hipLaunchKernelGGL(k_prep_fft, dim3(448),  dim3(256), 0, stream, w_fft, fragA_fft);
    hipLaunchKernelGGL(k_prep_mot, dim3(960),  dim3(256), 0, stream, w_motif, fragA_mot);
    hipLaunchKernelGGL(k_x2b,      dim3(4096), dim3(256), 0, stream, x, xb,
                       (int)(32 * 4 * LEN / 8));

    for (int b0 = 0; b0 < 32; b0 += nb) {
        int nbb = (32 - b0 < nb) ? (32 - b0) : nb;
        hipLaunchKernelGGL(k_motif_mfma, dim3(16, nbb, 10), dim3(256), 0, stream,
                           xb, fragA_mot, b_motif, y, b0);
        hipLaunchKernelGGL(k_reduce, dim3(32, nbb), dim3(256), 0, stream,
                           (const short*)y, w_reduce, b_reduce, s1);
        hipLaunchKernelGGL(k_fft, dim3(16, nbb), dim3(256), 0, stream,
                           (const short*)s1, fragA_fft, b_fft, s2);
        hipLaunchKernelGGL(k_gate, dim3(64, nbb), dim3(256), 0, stream,
                           (const unsigned short*)s2, w_expand, b_expand, y);
        hipLaunchKernelGGL(k_effect, dim3(16, nbb), dim3(256), 0, stream,
                           (const short*)y, fragA_eff, b_eff, out, b0);
    }
}